// Round 7
// baseline (255.595 us; speedup 1.0000x reference)
//
#include <hip/hip_runtime.h>
#include <stdint.h>

// Problem constants (B=4, N=16384, NP=4096) — ALL TENSORS FLOAT32.
#define QT   65536
#define NPTS 4096
#define C1   128
#define C2   256
#define CIN  384
#define COUT 128

typedef _Float16 f16;
typedef __attribute__((ext_vector_type(2))) _Float16 f16x2;
typedef __attribute__((ext_vector_type(8))) _Float16 f16x8;
typedef __attribute__((ext_vector_type(4))) float f32x4;

// Pre-packed (per-launch) weights, f16 in MFMA B-fragment order:
//   idx = ((kcb*NCB + cb)*64 + lane)*8 + e
//   holds W[(kcb*32 + (lane>>4)*8 + e) * N + cb*16 + (lane&15)]
__device__ __attribute__((aligned(16))) f16 g_w1p[12 * 16 * 64 * 8];
__device__ __attribute__((aligned(16))) f16 g_w2p[8 * 16 * 64 * 8];
__device__ __attribute__((aligned(16))) f16 g_w3p[8 * 8 * 64 * 8];
// Candidate table for the v_dot2 scan: per point
//   {u32 [cx,cy]f16, u32 [cz,0]f16, u32 bits(|p|^2 f32), 0}. 256 KB, L2-resident,
// read via wave-uniform pointer (scalar pipe).
__device__ __attribute__((aligned(16))) uint4 g_candh[4 * NPTS];

__device__ inline void packW4(const float* __restrict__ W, f16* __restrict__ dst,
                              int i, int N, int NCB) {
  const int g = i & 3, quad = (i >> 2) & 3, cbk = i >> 4;
  const int cb = cbk % NCB, kcb = cbk / NCB;
  const int col = cb * 16 + g * 4;
  const int k0 = kcb * 32 + quad * 8;
  f16x8 o[4];
#pragma unroll
  for (int e = 0; e < 8; ++e) {
    float4 v = *(const float4*)(W + (size_t)(k0 + e) * N + col);
    o[0][e] = (f16)v.x; o[1][e] = (f16)v.y; o[2][e] = (f16)v.z; o[3][e] = (f16)v.w;
  }
  f16* base = dst + ((size_t)cbk * 64 + quad * 16 + g * 4) * 8;
#pragma unroll
  for (int j = 0; j < 4; ++j) *(f16x8*)(base + j * 8) = o[j];
}

__device__ inline uint32_t h16(f16 v) {
  return (uint32_t)__builtin_bit_cast(uint16_t, v);
}

__global__ __launch_bounds__(256) void prep(
    const float* __restrict__ xyz2, const float* __restrict__ W1,
    const float* __restrict__ W2,   const float* __restrict__ W3) {
  const int tid = blockIdx.x * 256 + threadIdx.x;
  const int nthr = gridDim.x * 256;
  for (int i = tid; i < 4 * NPTS; i += nthr) {
    const float* p = xyz2 + (size_t)i * 3;
    float x = p[0], y = p[1], z = p[2];
    uint4 u;
    u.x = h16((f16)x) | (h16((f16)y) << 16);
    u.y = h16((f16)z);
    u.z = __builtin_bit_cast(uint32_t, fmaf(x, x, fmaf(y, y, z * z)));
    u.w = 0u;
    g_candh[i] = u;
  }
  for (int i = tid; i < 12 * 16 * 16; i += nthr) packW4(W1, g_w1p, i, 256, 16);
  for (int i = tid; i < 8 * 16 * 16; i += nthr) packW4(W2, g_w2p, i, 256, 16);
  for (int i = tid; i < 8 * 8 * 16; i += nthr) packW4(W3, g_w3p, i, 128, 8);
}

__device__ inline uint32_t umin(uint32_t a, uint32_t b) { return a < b ? a : b; }
__device__ inline uint32_t med3u(uint32_t a, uint32_t b, uint32_t c) {
  uint32_t d;
  asm("v_med3_u32 %0, %1, %2, %3" : "=v"(d) : "v"(a), "v"(b), "v"(c));
  return d;
}

// LDS overlay (phases strictly barrier-separated):
//  Phase A: mgU  u32[7][64][5]     @16384  (8960)   end 25344
//  persist: wv   f32[64][4]        @50176  (1024)
//           iv   i32[64][4]        @51200  (1024)   end 52224
//  Phase B: Xs f16[64][392]        @0      (50176)  (X = [f1|interp])
//           Hs f16[64][264]        @0      (33792)  (H1, then H2)
#define XS_STRIDE 392
#define HS_STRIDE 264
#define WV_OFF 50176
#define IV_OFF 51200
#define SMEM_BYTES 52224

__global__ __launch_bounds__(512) void fused_fp(
    const float* __restrict__ xyz1, const float* __restrict__ xyz2,
    const float* __restrict__ f1,   const float* __restrict__ f2,
    const float* __restrict__ W1,   const float* __restrict__ b1,
    const float* __restrict__ W2,   const float* __restrict__ b2,
    const float* __restrict__ W3,   const float* __restrict__ b3,
    float* __restrict__ out)
{
  __shared__ __align__(16) char smem[SMEM_BYTES];
  uint32_t* mgU  = (uint32_t*)(smem + 16384);
  float*    wvp  = (float*)(smem + WV_OFF);  // [64][4]
  int*      ivp  = (int*)(smem + IV_OFF);    // [64][4]
  f16*      Xs   = (f16*)smem;               // [64][XS_STRIDE]
  f16*      Hs   = (f16*)smem;               // [64][HS_STRIDE]

  const int t = threadIdx.x;
  const int r = t & 63;              // query row within block / lane id
  const int w = t >> 6;              // wave id 0..7
  const int qb = blockIdx.x * 64;
  const int batch = qb >> 14;        // 16384 queries per batch
  const float* xz2b = xyz2 + (size_t)batch * NPTS * 3;
  const float* f2b  = f2   + (size_t)batch * NPTS * C2;

  // ======================= Phase A: exact 3-NN =======================
  // Per-lane top-5 of packed keys over this wave's 512-candidate slice:
  //   e   = dot2([cx,cy]f16,[nx,ny]f16, dot2([cz,0]f16,[nz,0]f16, |q|^2+0.05))
  //         + |p|^2(f32)                      (always > 0: bias >> rounding)
  //   key = (bits(e) & 0xFFFFF000) | idx      (v_and_or, idx: 12 bits)
  // Constant +0.05 shift preserves per-lane ordering; f16 coord rounding
  // (<~1e-3 abs) only perturbs WHICH 40 survive — losing a true top-3 needs
  // 5 same-stream flips (P ~ 3e-7 kernel-wide) and the exact f64 rescore of
  // the 40 survivors (verbatim r2/r6, proven) fixes all ranking/ties.
  const int q = qb + r;
  const float qx = xyz1[q * 3], qy = xyz1[q * 3 + 1], qz = xyz1[q * 3 + 2];
  const float nx = -2.f * qx, ny = -2.f * qy, nz = -2.f * qz;
  const float sq1q = qx * qx + qy * qy + qz * qz;

  uint32_t k0 = ~0u, k1 = ~0u, k2 = ~0u, k3 = ~0u, k4 = ~0u;

  auto ins5 = [&](uint32_t c) {
    uint32_t n0 = umin(k0, c);
    uint32_t n1 = med3u(k0, k1, c);
    uint32_t n2 = med3u(k1, k2, c);
    uint32_t n3 = med3u(k2, k3, c);
    uint32_t n4 = med3u(k3, k4, c);
    k0 = n0; k1 = n1; k2 = n2; k3 = n3; k4 = n4;
  };

  {
    const int wu = __builtin_amdgcn_readfirstlane(w);   // force SGPR-uniform
    const uint4* __restrict__ cp = g_candh + (batch << 12) + (wu << 9);
    const uint32_t abase = (uint32_t)(wu << 9);
    f16x2 nxy; nxy[0] = (f16)nx; nxy[1] = (f16)ny;
    f16x2 nz0; nz0[0] = (f16)nz; nz0[1] = (f16)0.f;
    const float sbias = sq1q + 0.05f;
    uint32_t vmask = 0xFFFFF000u;
    asm("" : "+v"(vmask));               // pin mask in a VGPR (hoisted once)
    #pragma unroll 4
    for (int m = 0; m < 512; ++m) {
      uint4 u = cp[m];
#if __has_builtin(__builtin_amdgcn_fdot2)
      float acc = __builtin_amdgcn_fdot2(
          __builtin_bit_cast(f16x2, u.y), nz0, sbias, false);
      float e = __builtin_amdgcn_fdot2(
          __builtin_bit_cast(f16x2, u.x), nxy, acc, false);
#else
      f16x2 cxy = __builtin_bit_cast(f16x2, u.x);
      f16x2 cz0 = __builtin_bit_cast(f16x2, u.y);
      float e = fmaf((float)cxy[0], nx,
                fmaf((float)cxy[1], ny,
                fmaf((float)cz0[0], nz, sbias)));
#endif
      e += __builtin_bit_cast(float, u.z);
      uint32_t key;
      asm("v_and_or_b32 %0, %1, %2, %3"
          : "=v"(key)
          : "v"(__builtin_bit_cast(uint32_t, e)), "v"(vmask),
            "s"(abase + (uint32_t)m));
      ins5(key);
    }
  }

  if (w > 0) {
    int base = ((w - 1) * 64 + r) * 5;
    mgU[base]     = k0;
    mgU[base + 1] = k1;
    mgU[base + 2] = k2;
    mgU[base + 3] = k3;
    mgU[base + 4] = k4;
  }
  __syncthreads();

  if (w == 0) {
    // exact f64 rescore of the 40 survivors (selection exact; tie: low index)
    const double x1 = (double)qx, y1 = (double)qy, z1 = (double)qz;
    const double sq1 = x1 * x1 + y1 * y1 + z1 * z1;
    double d0 = 1e300, d1 = 1e300, d2 = 1e300;
    int j0 = 0, j1 = 0, j2 = 0;
    uint32_t surv[40];
    surv[0] = k0; surv[1] = k1; surv[2] = k2; surv[3] = k3; surv[4] = k4;
    #pragma unroll
    for (int wi = 0; wi < 7; ++wi)
      #pragma unroll
      for (int s = 0; s < 5; ++s)
        surv[5 + wi * 5 + s] = mgU[(wi * 64 + r) * 5 + s];
    #pragma unroll
    for (int s = 0; s < 40; ++s) {
      int idx = (int)(surv[s] & (NPTS - 1));
      const float* p2 = xz2b + (size_t)idx * 3;
      double x2 = (double)p2[0], y2 = (double)p2[1], z2 = (double)p2[2];
      double d = sq1 + (x2 * x2 + y2 * y2 + z2 * z2)
                     - 2.0 * (x1 * x2 + y1 * y2 + z1 * z2);
      bool c2 = (d < d2) || (d == d2 && idx < j2);
      bool c1 = (d < d1) || (d == d1 && idx < j1);
      bool c0 = (d < d0) || (d == d0 && idx < j0);
      d2 = c1 ? d1 : (c2 ? d : d2);  j2 = c1 ? j1 : (c2 ? idx : j2);
      d1 = c0 ? d0 : (c1 ? d : d1);  j1 = c0 ? j0 : (c1 ? idx : j1);
      d0 = c0 ? d : d0;              j0 = c0 ? idx : j0;
    }
    float e0 = fmaxf((float)d0, 1e-10f);
    float e1 = fmaxf((float)d1, 1e-10f);
    float e2 = fmaxf((float)d2, 1e-10f);
    float r0 = 1.f / e0, r1 = 1.f / e1, r2 = 1.f / e2;
    float inv = 1.f / (r0 + r1 + r2);
    wvp[r * 4 + 0] = r0 * inv; wvp[r * 4 + 1] = r1 * inv;
    wvp[r * 4 + 2] = r2 * inv; wvp[r * 4 + 3] = 0.f;
    ivp[r * 4 + 0] = j0; ivp[r * 4 + 1] = j1; ivp[r * 4 + 2] = j2; ivp[r * 4 + 3] = 0;
  }
  __syncthreads();

  // ============ Build X = [f1 | interp] once per block (f16 in LDS) ============
  {
    const int row = t >> 3, c = t & 7;
    f16* xr = Xs + row * XS_STRIDE;
    {
      const float* f1r = f1 + (size_t)(qb + row) * C1 + c * 16;
      float4 u0 = *(const float4*)(f1r);
      float4 u1 = *(const float4*)(f1r + 4);
      float4 u2 = *(const float4*)(f1r + 8);
      float4 u3 = *(const float4*)(f1r + 12);
      f16x8 o0, o1;
      o0[0] = (f16)u0.x; o0[1] = (f16)u0.y; o0[2] = (f16)u0.z; o0[3] = (f16)u0.w;
      o0[4] = (f16)u1.x; o0[5] = (f16)u1.y; o0[6] = (f16)u1.z; o0[7] = (f16)u1.w;
      o1[0] = (f16)u2.x; o1[1] = (f16)u2.y; o1[2] = (f16)u2.z; o1[3] = (f16)u2.w;
      o1[4] = (f16)u3.x; o1[5] = (f16)u3.y; o1[6] = (f16)u3.z; o1[7] = (f16)u3.w;
      *(f16x8*)(xr + c * 16)     = o0;
      *(f16x8*)(xr + c * 16 + 8) = o1;
    }
    const float w0 = wvp[row * 4 + 0], w1 = wvp[row * 4 + 1], w2 = wvp[row * 4 + 2];
    const float* p0 = f2b + (size_t)(ivp[row * 4 + 0] & (NPTS - 1)) * C2;
    const float* p1 = f2b + (size_t)(ivp[row * 4 + 1] & (NPTS - 1)) * C2;
    const float* p2 = f2b + (size_t)(ivp[row * 4 + 2] & (NPTS - 1)) * C2;
    #pragma unroll
    for (int ch = 0; ch < 4; ++ch) {
      const int col = ch * 64 + c * 8;
      float4 a0 = *(const float4*)(p0 + col), b0 = *(const float4*)(p0 + col + 4);
      float4 a1 = *(const float4*)(p1 + col), b1v = *(const float4*)(p1 + col + 4);
      float4 a2 = *(const float4*)(p2 + col), b2v = *(const float4*)(p2 + col + 4);
      f16x8 o;
      o[0] = (f16)(w0 * a0.x + w1 * a1.x + w2 * a2.x);
      o[1] = (f16)(w0 * a0.y + w1 * a1.y + w2 * a2.y);
      o[2] = (f16)(w0 * a0.z + w1 * a1.z + w2 * a2.z);
      o[3] = (f16)(w0 * a0.w + w1 * a1.w + w2 * a2.w);
      o[4] = (f16)(w0 * b0.x + w1 * b1v.x + w2 * b2v.x);
      o[5] = (f16)(w0 * b0.y + w1 * b1v.y + w2 * b2v.y);
      o[6] = (f16)(w0 * b0.z + w1 * b1v.z + w2 * b2v.z);
      o[7] = (f16)(w0 * b0.w + w1 * b1v.w + w2 * b2v.w);
      *(f16x8*)(xr + C1 + col) = o;
    }
  }
  __syncthreads();

  // ======================= Phase B: MLP via f16 MFMA ========================
  const int l16 = r & 15, quad = r >> 4;
  const int nb = w * 32;

  // ---- Layer 1: H1 = relu(X @ W1 + b1), K=384
  f32x4 acc[4][2];
  #pragma unroll
  for (int i = 0; i < 4; ++i)
    #pragma unroll
    for (int j = 0; j < 2; ++j) acc[i][j] = f32x4{0.f, 0.f, 0.f, 0.f};

  #pragma unroll
  for (int kc = 0; kc < CIN; kc += 32) {
    f16x8 a[4];
    #pragma unroll
    for (int i = 0; i < 4; ++i)
      a[i] = *(const f16x8*)(Xs + (i * 16 + l16) * XS_STRIDE + kc + quad * 8);
    f16x8 b[2];
    #pragma unroll
    for (int j = 0; j < 2; ++j)
      b[j] = *((const f16x8*)g_w1p +
               (size_t)((kc >> 5) * 16 + (w * 2 + j)) * 64 + r);
    #pragma unroll
    for (int i = 0; i < 4; ++i)
      #pragma unroll
      for (int j = 0; j < 2; ++j)
        acc[i][j] = __builtin_amdgcn_mfma_f32_16x16x32_f16(a[i], b[j], acc[i][j], 0, 0, 0);
  }
  __syncthreads();                         // all Xs reads done before Hs overwrite
  #pragma unroll
  for (int j = 0; j < 2; ++j) {
    float bv = b1[nb + j * 16 + l16];
    #pragma unroll
    for (int i = 0; i < 4; ++i)
      #pragma unroll
      for (int e = 0; e < 4; ++e) {
        int row = i * 16 + quad * 4 + e;
        Hs[row * HS_STRIDE + nb + j * 16 + l16] =
            (f16)fmaxf(acc[i][j][e] + bv, 0.f);
      }
  }
  __syncthreads();

  // ---- Layer 2: H2 = relu(H1 @ W2 + b2), K=256
  f32x4 acc2[4][2];
  #pragma unroll
  for (int i = 0; i < 4; ++i)
    #pragma unroll
    for (int j = 0; j < 2; ++j) acc2[i][j] = f32x4{0.f, 0.f, 0.f, 0.f};

  #pragma unroll
  for (int kc = 0; kc < 256; kc += 32) {
    f16x8 a[4];
    #pragma unroll
    for (int i = 0; i < 4; ++i)
      a[i] = *(const f16x8*)(Hs + (i * 16 + l16) * HS_STRIDE + kc + quad * 8);
    f16x8 b[2];
    #pragma unroll
    for (int j = 0; j < 2; ++j)
      b[j] = *((const f16x8*)g_w2p +
               (size_t)((kc >> 5) * 16 + (w * 2 + j)) * 64 + r);
    #pragma unroll
    for (int i = 0; i < 4; ++i)
      #pragma unroll
      for (int j = 0; j < 2; ++j)
        acc2[i][j] = __builtin_amdgcn_mfma_f32_16x16x32_f16(a[i], b[j], acc2[i][j], 0, 0, 0);
  }
  __syncthreads();                         // all H1 reads done before overwrite
  #pragma unroll
  for (int j = 0; j < 2; ++j) {
    float bv = b2[nb + j * 16 + l16];
    #pragma unroll
    for (int i = 0; i < 4; ++i)
      #pragma unroll
      for (int e = 0; e < 4; ++e) {
        int row = i * 16 + quad * 4 + e;
        Hs[row * HS_STRIDE + nb + j * 16 + l16] =
            (f16)fmaxf(acc2[i][j][e] + bv, 0.f);
      }
  }
  __syncthreads();

  // ---- Layer 3: OUT = H2 @ W3 + b3, K=256 (wave owns 16 cols)
  const int nb3 = w * 16;
  f32x4 acc3[4];
  #pragma unroll
  for (int i = 0; i < 4; ++i) acc3[i] = f32x4{0.f, 0.f, 0.f, 0.f};

  #pragma unroll
  for (int kc = 0; kc < 256; kc += 32) {
    f16x8 a[4];
    #pragma unroll
    for (int i = 0; i < 4; ++i)
      a[i] = *(const f16x8*)(Hs + (i * 16 + l16) * HS_STRIDE + kc + quad * 8);
    f16x8 b;
    b = *((const f16x8*)g_w3p + (size_t)((kc >> 5) * 8 + w) * 64 + r);
    #pragma unroll
    for (int i = 0; i < 4; ++i)
      acc3[i] = __builtin_amdgcn_mfma_f32_16x16x32_f16(a[i], b, acc3[i], 0, 0, 0);
  }
  {
    int col = nb3 + l16;
    float bv = b3[col];
    #pragma unroll
    for (int i = 0; i < 4; ++i)
      #pragma unroll
      for (int e = 0; e < 4; ++e) {
        int row = i * 16 + quad * 4 + e;
        out[(size_t)(qb + row) * COUT + col] = acc3[i][e] + bv;
      }
  }
}

// ---------------------------------------------------------------------------
extern "C" void kernel_launch(void* const* d_in, const int* in_sizes, int n_in,
                              void* d_out, int out_size, void* d_ws, size_t ws_size,
                              hipStream_t stream)
{
  (void)out_size; (void)d_ws; (void)ws_size;
  static const int expect[10] = {196608, 49152, 8388608, 4194304,
                                 98304, 256, 65536, 256, 32768, 128};
  const void* p[10];
  bool ok = (n_in == 10);
  if (ok) {
    bool used[10] = {false};
    for (int e = 0; e < 10; ++e) {
      p[e] = nullptr;
      for (int i = 0; i < 10; ++i) {
        if (!used[i] && in_sizes[i] == expect[e]) {
          p[e] = d_in[i]; used[i] = true; break;
        }
      }
      if (!p[e]) { ok = false; break; }
    }
  }
  if (!ok)
    for (int e = 0; e < 10; ++e) p[e] = d_in[e < n_in ? e : (n_in - 1)];

  prep<<<256, 256, 0, stream>>>(
      (const float*)p[1], (const float*)p[4],
      (const float*)p[6], (const float*)p[8]);

  fused_fp<<<QT / 64, 512, 0, stream>>>(
      (const float*)p[0], (const float*)p[1],
      (const float*)p[2], (const float*)p[3],
      (const float*)p[4], (const float*)p[5],
      (const float*)p[6], (const float*)p[7],
      (const float*)p[8], (const float*)p[9],
      (float*)d_out);
}

// Round 8
// 215.000 us; speedup vs baseline: 1.1888x; 1.1888x over previous
//
#include <hip/hip_runtime.h>
#include <stdint.h>

// Problem constants (B=4, N=16384, NP=4096) — ALL TENSORS FLOAT32.
#define QT   65536
#define NPTS 4096
#define C1   128
#define C2   256
#define CIN  384
#define COUT 128

typedef _Float16 f16;
typedef __attribute__((ext_vector_type(8))) _Float16 f16x8;
typedef __attribute__((ext_vector_type(4))) float f32x4;

// Pre-packed (per-launch) weights, f16 in MFMA B-fragment order:
//   idx = ((kcb*NCB + cb)*64 + lane)*8 + e
//   holds W[(kcb*32 + (lane>>4)*8 + e) * N + cb*16 + (lane&15)]
// -> a wave's fragment (kcb, cb) is one contiguous 1KB block; lane reads
//    16B at lane*16 -> single global_load_dwordx4, L2-resident.
__device__ __attribute__((aligned(16))) f16 g_w1p[12 * 16 * 64 * 8];
__device__ __attribute__((aligned(16))) f16 g_w2p[8 * 16 * 64 * 8];
__device__ __attribute__((aligned(16))) f16 g_w3p[8 * 8 * 64 * 8];
// Candidate table: (x, y, z, |p|^2) per xyz2 point, per batch. 256 KB,
// L2-resident. Read via wave-uniform pointer in the scan (scalar pipe).
__device__ __attribute__((aligned(16))) float4 g_cand[4 * NPTS];

// packW4: one iteration packs 4 lanes (consecutive cols) of one fragment,
// reading float4 from W (coalesced within the 4-col group).
__device__ inline void packW4(const float* __restrict__ W, f16* __restrict__ dst,
                              int i, int N, int NCB) {
  const int g = i & 3, quad = (i >> 2) & 3, cbk = i >> 4;
  const int cb = cbk % NCB, kcb = cbk / NCB;
  const int col = cb * 16 + g * 4;
  const int k0 = kcb * 32 + quad * 8;
  f16x8 o[4];
#pragma unroll
  for (int e = 0; e < 8; ++e) {
    float4 v = *(const float4*)(W + (size_t)(k0 + e) * N + col);
    o[0][e] = (f16)v.x; o[1][e] = (f16)v.y; o[2][e] = (f16)v.z; o[3][e] = (f16)v.w;
  }
  f16* base = dst + ((size_t)cbk * 64 + quad * 16 + g * 4) * 8;
#pragma unroll
  for (int j = 0; j < 4; ++j) *(f16x8*)(base + j * 8) = o[j];
}

__global__ __launch_bounds__(256) void prep(
    const float* __restrict__ xyz2, const float* __restrict__ W1,
    const float* __restrict__ W2,   const float* __restrict__ W3) {
  const int tid = blockIdx.x * 256 + threadIdx.x;
  const int nthr = gridDim.x * 256;
  for (int i = tid; i < 4 * NPTS; i += nthr) {
    const float* p = xyz2 + (size_t)i * 3;
    float x = p[0], y = p[1], z = p[2];
    g_cand[i] = make_float4(x, y, z, fmaf(x, x, fmaf(y, y, z * z)));
  }
  for (int i = tid; i < 12 * 16 * 16; i += nthr) packW4(W1, g_w1p, i, 256, 16);
  for (int i = tid; i < 8 * 16 * 16; i += nthr) packW4(W2, g_w2p, i, 256, 16);
  for (int i = tid; i < 8 * 8 * 16; i += nthr) packW4(W3, g_w3p, i, 128, 8);
}

__device__ inline uint32_t umin(uint32_t a, uint32_t b) { return a < b ? a : b; }
__device__ inline uint32_t med3u(uint32_t a, uint32_t b, uint32_t c) {
  uint32_t d;
  asm("v_med3_u32 %0, %1, %2, %3" : "=v"(d) : "v"(a), "v"(b), "v"(c));
  return d;
}

// LDS overlay (phases strictly barrier-separated):
//  Phase A: dmpD f64[8][64][3]     @16384  (12288)  per-wave top-3 dists
//           dmpI i32[8][64][3]     @28672  (6144)   per-wave top-3 idx
//  persist: wv   f32[64][4]        @50176  (1024)
//           iv   i32[64][4]        @51200  (1024)   end 52224
//  Phase B: Xs f16[64][392]        @0      (50176)  (X = [f1|interp])
//           Hs f16[64][264]        @0      (33792)  (H1, then H2)
#define XS_STRIDE 392
#define HS_STRIDE 264
#define DMPD_OFF 16384
#define DMPI_OFF 28672
#define WV_OFF 50176
#define IV_OFF 51200
#define SMEM_BYTES 52224

__global__ __launch_bounds__(512) void fused_fp(
    const float* __restrict__ xyz1, const float* __restrict__ xyz2,
    const float* __restrict__ f1,   const float* __restrict__ f2,
    const float* __restrict__ W1,   const float* __restrict__ b1,
    const float* __restrict__ W2,   const float* __restrict__ b2,
    const float* __restrict__ W3,   const float* __restrict__ b3,
    float* __restrict__ out)
{
  __shared__ __align__(16) char smem[SMEM_BYTES];
  double*   dmpD = (double*)(smem + DMPD_OFF);  // [8][64][3]
  int*      dmpI = (int*)(smem + DMPI_OFF);     // [8][64][3]
  float*    wvp  = (float*)(smem + WV_OFF);     // [64][4]
  int*      ivp  = (int*)(smem + IV_OFF);       // [64][4]
  f16*      Xs   = (f16*)smem;                  // [64][XS_STRIDE]
  f16*      Hs   = (f16*)smem;                  // [64][HS_STRIDE]

  const int t = threadIdx.x;
  const int r = t & 63;              // query row within block / lane id
  const int w = t >> 6;              // wave id 0..7
  const int qb = blockIdx.x * 64;
  const int batch = qb >> 14;        // 16384 queries per batch
  const float* xz2b = xyz2 + (size_t)batch * NPTS * 3;
  const float* f2b  = f2   + (size_t)batch * NPTS * C2;

  // ======================= Phase A: exact 3-NN =======================
  // Per-lane top-5 of packed keys over this wave's 512-candidate slice
  // (r6 scan, minus fmax):
  //   e   = fma(nx,cx, fma(ny,cy, fma(nz,cz, |p|^2))) + (|q|^2 + 0.05)
  //   key = (bits(e) & 0xFFFFF000) | idx        (compiler fuses to v_and_or)
  // +0.05 bias: e >= 0.04 > 0 always (rounding err ~1e-5), so u32 order ==
  // float order; correctly-rounded add is monotone (merges -> idx tiebreak,
  // never inverts). 12 dropped mantissa bits = 4.9e-4 relative quantization,
  // absorbed by depth-5 margin + exact f64 rescore (proven r2/r6).
  const int q = qb + r;
  const float qx = xyz1[q * 3], qy = xyz1[q * 3 + 1], qz = xyz1[q * 3 + 2];
  const float nx = -2.f * qx, ny = -2.f * qy, nz = -2.f * qz;
  const float sq1q = qx * qx + qy * qy + qz * qz;

  uint32_t k0 = ~0u, k1 = ~0u, k2 = ~0u, k3 = ~0u, k4 = ~0u;

  auto ins5 = [&](uint32_t c) {
    uint32_t n0 = umin(k0, c);
    uint32_t n1 = med3u(k0, k1, c);
    uint32_t n2 = med3u(k1, k2, c);
    uint32_t n3 = med3u(k2, k3, c);
    uint32_t n4 = med3u(k3, k4, c);
    k0 = n0; k1 = n1; k2 = n2; k3 = n3; k4 = n4;
  };
  auto packk = [&](float e, uint32_t idx) -> uint32_t {
    return (__builtin_bit_cast(uint32_t, e) & 0xFFFFF000u) | idx;
  };

  {
    const int wu = __builtin_amdgcn_readfirstlane(w);   // force SGPR-uniform
    const float4* __restrict__ cp = g_cand + (batch << 12) + (wu << 9);
    const uint32_t abase = (uint32_t)(wu << 9);
    const float sbias = sq1q + 0.05f;
    #pragma unroll 2
    for (int m = 0; m < 512; m += 4) {
      float4 c0 = cp[m], c1 = cp[m + 1], c2 = cp[m + 2], c3 = cp[m + 3];
      float e0 = fmaf(nx, c0.x, fmaf(ny, c0.y, fmaf(nz, c0.z, c0.w))) + sbias;
      float e1 = fmaf(nx, c1.x, fmaf(ny, c1.y, fmaf(nz, c1.z, c1.w))) + sbias;
      float e2 = fmaf(nx, c2.x, fmaf(ny, c2.y, fmaf(nz, c2.z, c2.w))) + sbias;
      float e3 = fmaf(nx, c3.x, fmaf(ny, c3.y, fmaf(nz, c3.z, c3.w))) + sbias;
      ins5(packk(e0, abase + m));
      ins5(packk(e1, abase + m + 1));
      ins5(packk(e2, abase + m + 2));
      ins5(packk(e3, abase + m + 3));
    }
  }

  // ---- Stage 1 (ALL waves, parallel): exact f64 rescore of this wave's
  // own 5 register-held survivors for query r -> per-wave top-3 (d, idx),
  // total order (d, then low idx). Every wave's 5 slots hold real stream
  // candidates (512 >= 5), all idx distinct across waves.
  {
    const double x1 = (double)qx, y1 = (double)qy, z1 = (double)qz;
    const double sq1 = x1 * x1 + y1 * y1 + z1 * z1;
    double d0 = 1e300, d1 = 1e300, d2 = 1e300;
    int j0 = 0, j1 = 0, j2 = 0;
    uint32_t sv[5] = {k0, k1, k2, k3, k4};
    #pragma unroll
    for (int s = 0; s < 5; ++s) {
      int idx = (int)(sv[s] & (NPTS - 1));
      const float* p2 = xz2b + (size_t)idx * 3;
      double x2 = (double)p2[0], y2 = (double)p2[1], z2 = (double)p2[2];
      double d = sq1 + (x2 * x2 + y2 * y2 + z2 * z2)
                     - 2.0 * (x1 * x2 + y1 * y2 + z1 * z2);
      bool c2 = (d < d2) || (d == d2 && idx < j2);
      bool c1 = (d < d1) || (d == d1 && idx < j1);
      bool c0 = (d < d0) || (d == d0 && idx < j0);
      d2 = c1 ? d1 : (c2 ? d : d2);  j2 = c1 ? j1 : (c2 ? idx : j2);
      d1 = c0 ? d0 : (c1 ? d : d1);  j1 = c0 ? j0 : (c1 ? idx : j1);
      d0 = c0 ? d : d0;              j0 = c0 ? idx : j0;
    }
    const int base = (w * 64 + r) * 3;
    dmpD[base]     = d0;  dmpI[base]     = j0;
    dmpD[base + 1] = d1;  dmpI[base + 1] = j1;
    dmpD[base + 2] = d2;  dmpI[base + 2] = j2;
  }
  __syncthreads();

  // ---- Stage 2 (wave 0): merge the 24 (d, idx) pairs from LDS (no global
  // loads, no recompute). top3(union) == top3(union of per-group top3) under
  // the same total order -> bit-identical to the single-stage 40-rescore.
  if (w == 0) {
    double d0 = 1e300, d1 = 1e300, d2 = 1e300;
    int j0 = 0, j1 = 0, j2 = 0;
    #pragma unroll
    for (int w2 = 0; w2 < 8; ++w2) {
      #pragma unroll
      for (int s = 0; s < 3; ++s) {
        const int base = (w2 * 64 + r) * 3 + s;
        double d = dmpD[base];
        int idx  = dmpI[base];
        bool c2 = (d < d2) || (d == d2 && idx < j2);
        bool c1 = (d < d1) || (d == d1 && idx < j1);
        bool c0 = (d < d0) || (d == d0 && idx < j0);
        d2 = c1 ? d1 : (c2 ? d : d2);  j2 = c1 ? j1 : (c2 ? idx : j2);
        d1 = c0 ? d0 : (c1 ? d : d1);  j1 = c0 ? j0 : (c1 ? idx : j1);
        d0 = c0 ? d : d0;              j0 = c0 ? idx : j0;
      }
    }
    float e0 = fmaxf((float)d0, 1e-10f);
    float e1 = fmaxf((float)d1, 1e-10f);
    float e2 = fmaxf((float)d2, 1e-10f);
    float r0 = 1.f / e0, r1 = 1.f / e1, r2 = 1.f / e2;
    float inv = 1.f / (r0 + r1 + r2);
    wvp[r * 4 + 0] = r0 * inv; wvp[r * 4 + 1] = r1 * inv;
    wvp[r * 4 + 2] = r2 * inv; wvp[r * 4 + 3] = 0.f;
    ivp[r * 4 + 0] = j0; ivp[r * 4 + 1] = j1; ivp[r * 4 + 2] = j2; ivp[r * 4 + 3] = 0;
  }
  __syncthreads();

  // ============ Build X = [f1 | interp] once per block (f16 in LDS) ============
  // 8 threads per row. f1: direct f32 load + cast. Interp: f32 weighted sum,
  // then one f16 cast — identical numerics to r2/r6 (passing).
  {
    const int row = t >> 3, c = t & 7;
    f16* xr = Xs + row * XS_STRIDE;
    {
      const float* f1r = f1 + (size_t)(qb + row) * C1 + c * 16;
      float4 u0 = *(const float4*)(f1r);
      float4 u1 = *(const float4*)(f1r + 4);
      float4 u2 = *(const float4*)(f1r + 8);
      float4 u3 = *(const float4*)(f1r + 12);
      f16x8 o0, o1;
      o0[0] = (f16)u0.x; o0[1] = (f16)u0.y; o0[2] = (f16)u0.z; o0[3] = (f16)u0.w;
      o0[4] = (f16)u1.x; o0[5] = (f16)u1.y; o0[6] = (f16)u1.z; o0[7] = (f16)u1.w;
      o1[0] = (f16)u2.x; o1[1] = (f16)u2.y; o1[2] = (f16)u2.z; o1[3] = (f16)u2.w;
      o1[4] = (f16)u3.x; o1[5] = (f16)u3.y; o1[6] = (f16)u3.z; o1[7] = (f16)u3.w;
      *(f16x8*)(xr + c * 16)     = o0;
      *(f16x8*)(xr + c * 16 + 8) = o1;
    }
    const float w0 = wvp[row * 4 + 0], w1 = wvp[row * 4 + 1], w2 = wvp[row * 4 + 2];
    const float* p0 = f2b + (size_t)(ivp[row * 4 + 0] & (NPTS - 1)) * C2;
    const float* p1 = f2b + (size_t)(ivp[row * 4 + 1] & (NPTS - 1)) * C2;
    const float* p2 = f2b + (size_t)(ivp[row * 4 + 2] & (NPTS - 1)) * C2;
    #pragma unroll
    for (int ch = 0; ch < 4; ++ch) {
      const int col = ch * 64 + c * 8;
      float4 a0 = *(const float4*)(p0 + col), b0 = *(const float4*)(p0 + col + 4);
      float4 a1 = *(const float4*)(p1 + col), b1v = *(const float4*)(p1 + col + 4);
      float4 a2 = *(const float4*)(p2 + col), b2v = *(const float4*)(p2 + col + 4);
      f16x8 o;
      o[0] = (f16)(w0 * a0.x + w1 * a1.x + w2 * a2.x);
      o[1] = (f16)(w0 * a0.y + w1 * a1.y + w2 * a2.y);
      o[2] = (f16)(w0 * a0.z + w1 * a1.z + w2 * a2.z);
      o[3] = (f16)(w0 * a0.w + w1 * a1.w + w2 * a2.w);
      o[4] = (f16)(w0 * b0.x + w1 * b1v.x + w2 * b2v.x);
      o[5] = (f16)(w0 * b0.y + w1 * b1v.y + w2 * b2v.y);
      o[6] = (f16)(w0 * b0.z + w1 * b1v.z + w2 * b2v.z);
      o[7] = (f16)(w0 * b0.w + w1 * b1v.w + w2 * b2v.w);
      *(f16x8*)(xr + C1 + col) = o;
    }
  }
  __syncthreads();

  // ======================= Phase B: MLP via f16 MFMA ========================
  // M=64 rows; wave w owns output cols [w*32,+32) in L1/L2, [w*16,+16) in L3.
  const int l16 = r & 15, quad = r >> 4;
  const int nb = w * 32;

  // ---- Layer 1: H1 = relu(X @ W1 + b1), K=384
  f32x4 acc[4][2];
  #pragma unroll
  for (int i = 0; i < 4; ++i)
    #pragma unroll
    for (int j = 0; j < 2; ++j) acc[i][j] = f32x4{0.f, 0.f, 0.f, 0.f};

  #pragma unroll
  for (int kc = 0; kc < CIN; kc += 32) {
    f16x8 a[4];
    #pragma unroll
    for (int i = 0; i < 4; ++i)
      a[i] = *(const f16x8*)(Xs + (i * 16 + l16) * XS_STRIDE + kc + quad * 8);
    f16x8 b[2];
    #pragma unroll
    for (int j = 0; j < 2; ++j)
      b[j] = *((const f16x8*)g_w1p +
               (size_t)((kc >> 5) * 16 + (w * 2 + j)) * 64 + r);
    #pragma unroll
    for (int i = 0; i < 4; ++i)
      #pragma unroll
      for (int j = 0; j < 2; ++j)
        acc[i][j] = __builtin_amdgcn_mfma_f32_16x16x32_f16(a[i], b[j], acc[i][j], 0, 0, 0);
  }
  __syncthreads();                         // all Xs reads done before Hs overwrite
  #pragma unroll
  for (int j = 0; j < 2; ++j) {
    float bv = b1[nb + j * 16 + l16];
    #pragma unroll
    for (int i = 0; i < 4; ++i)
      #pragma unroll
      for (int e = 0; e < 4; ++e) {
        int row = i * 16 + quad * 4 + e;
        Hs[row * HS_STRIDE + nb + j * 16 + l16] =
            (f16)fmaxf(acc[i][j][e] + bv, 0.f);
      }
  }
  __syncthreads();

  // ---- Layer 2: H2 = relu(H1 @ W2 + b2), K=256
  f32x4 acc2[4][2];
  #pragma unroll
  for (int i = 0; i < 4; ++i)
    #pragma unroll
    for (int j = 0; j < 2; ++j) acc2[i][j] = f32x4{0.f, 0.f, 0.f, 0.f};

  #pragma unroll
  for (int kc = 0; kc < 256; kc += 32) {
    f16x8 a[4];
    #pragma unroll
    for (int i = 0; i < 4; ++i)
      a[i] = *(const f16x8*)(Hs + (i * 16 + l16) * HS_STRIDE + kc + quad * 8);
    f16x8 b[2];
    #pragma unroll
    for (int j = 0; j < 2; ++j)
      b[j] = *((const f16x8*)g_w2p +
               (size_t)((kc >> 5) * 16 + (w * 2 + j)) * 64 + r);
    #pragma unroll
    for (int i = 0; i < 4; ++i)
      #pragma unroll
      for (int j = 0; j < 2; ++j)
        acc2[i][j] = __builtin_amdgcn_mfma_f32_16x16x32_f16(a[i], b[j], acc2[i][j], 0, 0, 0);
  }
  __syncthreads();                         // all H1 reads done before overwrite
  #pragma unroll
  for (int j = 0; j < 2; ++j) {
    float bv = b2[nb + j * 16 + l16];
    #pragma unroll
    for (int i = 0; i < 4; ++i)
      #pragma unroll
      for (int e = 0; e < 4; ++e) {
        int row = i * 16 + quad * 4 + e;
        Hs[row * HS_STRIDE + nb + j * 16 + l16] =
            (f16)fmaxf(acc2[i][j][e] + bv, 0.f);
      }
  }
  __syncthreads();

  // ---- Layer 3: OUT = H2 @ W3 + b3, K=256 (wave owns 16 cols)
  const int nb3 = w * 16;
  f32x4 acc3[4];
  #pragma unroll
  for (int i = 0; i < 4; ++i) acc3[i] = f32x4{0.f, 0.f, 0.f, 0.f};

  #pragma unroll
  for (int kc = 0; kc < 256; kc += 32) {
    f16x8 a[4];
    #pragma unroll
    for (int i = 0; i < 4; ++i)
      a[i] = *(const f16x8*)(Hs + (i * 16 + l16) * HS_STRIDE + kc + quad * 8);
    f16x8 b;
    b = *((const f16x8*)g_w3p + (size_t)((kc >> 5) * 8 + w) * 64 + r);
    #pragma unroll
    for (int i = 0; i < 4; ++i)
      acc3[i] = __builtin_amdgcn_mfma_f32_16x16x32_f16(a[i], b, acc3[i], 0, 0, 0);
  }
  {
    int col = nb3 + l16;
    float bv = b3[col];
    #pragma unroll
    for (int i = 0; i < 4; ++i)
      #pragma unroll
      for (int e = 0; e < 4; ++e) {
        int row = i * 16 + quad * 4 + e;
        out[(size_t)(qb + row) * COUT + col] = acc3[i][e] + bv;
      }
  }
}

// ---------------------------------------------------------------------------
extern "C" void kernel_launch(void* const* d_in, const int* in_sizes, int n_in,
                              void* d_out, int out_size, void* d_ws, size_t ws_size,
                              hipStream_t stream)
{
  (void)out_size; (void)d_ws; (void)ws_size;
  static const int expect[10] = {196608, 49152, 8388608, 4194304,
                                 98304, 256, 65536, 256, 32768, 128};
  const void* p[10];
  bool ok = (n_in == 10);
  if (ok) {
    bool used[10] = {false};
    for (int e = 0; e < 10; ++e) {
      p[e] = nullptr;
      for (int i = 0; i < 10; ++i) {
        if (!used[i] && in_sizes[i] == expect[e]) {
          p[e] = d_in[i]; used[i] = true; break;
        }
      }
      if (!p[e]) { ok = false; break; }
    }
  }
  if (!ok)
    for (int e = 0; e < 10; ++e) p[e] = d_in[e < n_in ? e : (n_in - 1)];

  prep<<<256, 256, 0, stream>>>(
      (const float*)p[1], (const float*)p[4],
      (const float*)p[6], (const float*)p[8]);

  fused_fp<<<QT / 64, 512, 0, stream>>>(
      (const float*)p[0], (const float*)p[1],
      (const float*)p[2], (const float*)p[3],
      (const float*)p[4], (const float*)p[5],
      (const float*)p[6], (const float*)p[7],
      (const float*)p[8], (const float*)p[9],
      (float*)d_out);
}